// Round 1
// baseline (669.460 us; speedup 1.0000x reference)
//
#include <hip/hip_runtime.h>
#include <math.h>

// Problem shape (fixed by setup_inputs): B=32, C=200, H=128, W=128, fp32.
// One block per (b,c) plane. 256 threads x 64 elements = 16384 = 128*128.
// Single pass over HBM: plane held in registers (16 float4/thread) across
// the min/max reduction, then normalized + stored + centroid-accumulated.

#define HW_ELEMS 16384   // 128*128
#define WDIM 128

__global__ __launch_bounds__(256) void cm2kp_kernel(
    const float* __restrict__ in,
    float* __restrict__ map_out,
    float* __restrict__ kp_out,
    float* __restrict__ zeta_out)
{
    const int bc = blockIdx.x;
    const float4* __restrict__ src = (const float4*)(in + (size_t)bc * HW_ELEMS);
    float4* __restrict__ dst = (float4*)(map_out + (size_t)bc * HW_ELEMS);
    const int t = threadIdx.x;
    const int wave = t >> 6;
    const int lane = t & 63;

    // ---- Phase 1: load plane into registers, per-thread min/max ----
    float4 v[16];
    float vmin =  3.402823466e38f;
    float vmax = -3.402823466e38f;
    #pragma unroll
    for (int i = 0; i < 16; ++i) {
        v[i] = src[i * 256 + t];                       // coalesced 16B/lane
        vmin = fminf(vmin, fminf(fminf(v[i].x, v[i].y), fminf(v[i].z, v[i].w)));
        vmax = fmaxf(vmax, fmaxf(fmaxf(v[i].x, v[i].y), fmaxf(v[i].z, v[i].w)));
    }

    // wave (64-lane) reduce min/max
    #pragma unroll
    for (int off = 32; off > 0; off >>= 1) {
        vmin = fminf(vmin, __shfl_down(vmin, off, 64));
        vmax = fmaxf(vmax, __shfl_down(vmax, off, 64));
    }
    __shared__ float smin[4], smax[4];
    if (lane == 0) { smin[wave] = vmin; smax[wave] = vmax; }
    __syncthreads();
    const float bmin = fminf(fminf(smin[0], smin[1]), fminf(smin[2], smin[3]));
    const float bmax = fmaxf(fmaxf(smax[0], smax[1]), fmaxf(smax[2], smax[3]));
    // Reference divides by max (NOT max-min). One IEEE divide per block,
    // then multiply: <=1 ulp extra error vs per-element divide.
    const float inv = 1.0f / bmax;

    // ---- Phase 2: normalize, store, accumulate zeta / kp_x / kp_y ----
    float zeta = 0.0f, kpx = 0.0f, kpy = 0.0f;
    #pragma unroll
    for (int i = 0; i < 16; ++i) {
        const int e = (i * 256 + t) * 4;               // element offset in plane
        const float x0 = (float)(e & (WDIM - 1));      // w coord (no wrap: 128%4==0)
        const float y0 = (float)(e >> 7);              // h coord
        float4 m;
        m.x = (v[i].x - bmin) * inv;
        m.y = (v[i].y - bmin) * inv;
        m.z = (v[i].z - bmin) * inv;
        m.w = (v[i].w - bmin) * inv;
        dst[i * 256 + t] = m;                          // coalesced 16B/lane
        const float s = m.x + m.y + m.z + m.w;
        zeta += s;
        kpx  += m.x * x0 + m.y * (x0 + 1.0f) + m.z * (x0 + 2.0f) + m.w * (x0 + 3.0f);
        kpy  += s * y0;
    }

    #pragma unroll
    for (int off = 32; off > 0; off >>= 1) {
        zeta += __shfl_down(zeta, off, 64);
        kpx  += __shfl_down(kpx,  off, 64);
        kpy  += __shfl_down(kpy,  off, 64);
    }
    __shared__ float sz[4], sx[4], sy[4];
    if (lane == 0) { sz[wave] = zeta; sx[wave] = kpx; sy[wave] = kpy; }
    __syncthreads();
    if (t == 0) {
        const float Z = sz[0] + sz[1] + sz[2] + sz[3];
        const float X = sx[0] + sx[1] + sx[2] + sx[3];
        const float Y = sy[0] + sy[1] + sy[2] + sy[3];
        zeta_out[bc] = Z;
        // jnp.round = half-to-even -> rintf (default FP rounding mode)
        kp_out[2 * bc + 0] = rintf(X / Z);
        kp_out[2 * bc + 1] = rintf(Y / Z);
    }
}

extern "C" void kernel_launch(void* const* d_in, const int* in_sizes, int n_in,
                              void* d_out, int out_size, void* d_ws, size_t ws_size,
                              hipStream_t stream) {
    const float* in = (const float*)d_in[0];
    const int BC = in_sizes[0] / HW_ELEMS;             // 32*200 = 6400
    float* map  = (float*)d_out;                       // [B,C,H,W]
    float* kp   = map + (size_t)BC * HW_ELEMS;         // [B,C,2]
    float* zeta = kp + (size_t)2 * BC;                 // [B,C]
    cm2kp_kernel<<<dim3(BC), dim3(256), 0, stream>>>(in, map, kp, zeta);
}